// Round 16
// baseline (273.341 us; speedup 1.0000x reference)
//
#include <hip/hip_runtime.h>
#include <hip/hip_fp16.h>
#include <math.h>

#define HH 512
#define WW 512
#define NIMG 8
#define NPIX (NIMG * HH * WW)          // 2,097,152
#define GAMMA_FLOW 0.001f
#define GAMMA_MASK 0.0005f
#define INV_TOTAL (1.0f / (float)(NPIX * 3))

#define HALF_PIX     (NPIX / 2)
#define CVT_BLOCKS   (NPIX / 256)      // 8192
#define CONVA_BLOCKS (HALF_PIX / 128)  // 8192 (images 0-3, 4 px/thread)
#define FAT_BLOCKS   (CVT_BLOCKS + CONVA_BLOCKS)  // 16384
#define CONV8_BLOCKS (HALF_PIX / 256)  // 4096 (images 4-7, 8 px/thread)

__device__ __forceinline__ float tanh_fast(float x)
{
    float e = __expf(2.0f * x);
    return 1.0f - 2.0f / (e + 1.0f);
}

__device__ __forceinline__ void fma12(float acc[3], const float wf[12],
                                      float4 x)
{
    float xv[4] = {x.x, x.y, x.z, x.w};
#pragma unroll
    for (int k = 0; k < 4; ++k) {
        acc[0] = fmaf(xv[k], wf[k * 3 + 0], acc[0]);
        acc[1] = fmaf(xv[k], wf[k * 3 + 1], acc[1]);
        acc[2] = fmaf(xv[k], wf[k * 3 + 2], acc[2]);
    }
}

// ========== K1 (fat, control): bid even -> cvt ; odd -> conv 4px (imgs 0-3) =
__global__ __launch_bounds__(256, 4) void fat_kernel(
    const float* __restrict__ enc, const float* __restrict__ cw,
    const float* __restrict__ cb, const float* __restrict__ frames,
    float* __restrict__ flow, float* __restrict__ mask,
    __half* __restrict__ f0h, __half* __restrict__ f1h,
    float* __restrict__ tv_out)
{
    int bid = blockIdx.x;

    if ((bid & 1) == 0) {
        // ---------------- cvt: fp32 NHWC(6) -> two planar fp16(4) ----------
        int ci = bid >> 1;                             // 0..8191
        int t  = ci * 256 + threadIdx.x;               // one pixel
        if (t == 0) tv_out[0] = 0.0f;
        const float2* fp = reinterpret_cast<const float2*>(frames + (size_t)t * 6);
        float2 v0 = fp[0], v1 = fp[1], v2 = fp[2];
        __half2 a = __floats2half2_rn(v0.x, v0.y);
        __half2 b = __floats2half2_rn(v1.x, 0.0f);
        __half2 c = __floats2half2_rn(v1.y, v2.x);
        __half2 d = __floats2half2_rn(v2.y, 0.0f);
        __half2* p0 = reinterpret_cast<__half2*>(f0h) + (size_t)t * 2;
        __half2* p1 = reinterpret_cast<__half2*>(f1h) + (size_t)t * 2;
        p0[0] = a; p0[1] = b;
        p1[0] = c; p1[1] = d;
        return;
    }

    // ---------------- conv 4 adjacent px/thread (r15 proven body) ----------
    int ci  = bid >> 1;                                   // 0..8191
    int wb  = (ci & 7) * (CONVA_BLOCKS / 8) + (ci >> 3);  // XCD swizzle
    int px0 = wb * 128;
    int n = px0 >> 18;
    int h = (px0 >> 9) & (HH - 1);

    int tid  = threadIdx.x;
    int wv   = tid >> 6;
    int lane = tid & 63;
    int pg   = lane >> 3;                                 // pixel group (0..7)
    int c4   = lane & 7;                                  // channel chunk

    int wbase = (px0 & (WW - 1)) + wv * 32;
    int pxb   = wbase + pg * 4;

    const float4* cwB = reinterpret_cast<const float4*>(cw) + c4 * 3;
    const float* imgbase = enc + ((size_t)n * HH) * (WW * 32);

    float acc[4][3];
#pragma unroll
    for (int p = 0; p < 4; ++p)
        acc[p][0] = acc[p][1] = acc[p][2] = 0.0f;

    bool edge = (wbase == 0) || (wbase == WW - 32);

#pragma unroll
    for (int kh = 0; kh < 3; ++kh) {
        int hr = h + kh - 1;
        if ((unsigned)hr >= (unsigned)HH) continue;
        const float* rowp = imgbase + (size_t)hr * (WW * 32);

        float4 win[6];
        if (!edge) {
            const float* pB = rowp + (pxb - 1) * 32 + c4 * 4;
#pragma unroll
            for (int j = 0; j < 6; ++j)
                win[j] = *reinterpret_cast<const float4*>(pB + j * 32);
        } else {
#pragma unroll
            for (int j = 0; j < 6; ++j) {
                int col = pxb + j - 1;
                win[j] = make_float4(0.f, 0.f, 0.f, 0.f);
                if ((unsigned)col < (unsigned)WW)
                    win[j] = *reinterpret_cast<const float4*>(
                                 rowp + (size_t)col * 32 + c4 * 4);
            }
        }

#pragma unroll
        for (int kw = 0; kw < 3; ++kw) {
            int t = kh * 3 + kw;
            float wf[12];
            *reinterpret_cast<float4*>(&wf[0]) = cwB[t * 24 + 0];
            *reinterpret_cast<float4*>(&wf[4]) = cwB[t * 24 + 1];
            *reinterpret_cast<float4*>(&wf[8]) = cwB[t * 24 + 2];
#pragma unroll
            for (int p = 0; p < 4; ++p)
                fma12(acc[p], wf, win[p + kw]);
        }
    }

    float b0 = cb[0], b1 = cb[1], b2 = cb[2];
    size_t rowidx = ((size_t)n * HH + h) * WW;

#pragma unroll
    for (int p = 0; p < 4; ++p) {
#pragma unroll
        for (int off = 1; off < 8; off <<= 1) {
            acc[p][0] += __shfl_xor(acc[p][0], off);
            acc[p][1] += __shfl_xor(acc[p][1], off);
            acc[p][2] += __shfl_xor(acc[p][2], off);
        }
    }
    if (c4 == 0) {
#pragma unroll
        for (int p = 0; p < 4; ++p) {
            size_t idx = rowidx + (size_t)(pxb + p);
            *reinterpret_cast<float2*>(flow + idx * 2) =
                make_float2(tanh_fast(acc[p][0] + b0),
                            tanh_fast(acc[p][1] + b1));
            mask[idx] = tanh_fast(acc[p][2] + b2);
        }
    }
}

// ========== K1b (experiment): conv 8 adjacent px/thread, imgs 4-7 ===========
// (256,2): budget 128 (law: 256/N). Needs ~90 live regs (win 40 + acc 24 +
// wf 12 + addr). Bet: 2x per-thread ILP (2 hoisted rows possible) beats the
// halved occupancy (r9: (256,2)@4px lost 23%; interp's ILP law suggests win).
__global__ __launch_bounds__(256, 2) void conv8_kernel(
    const float* __restrict__ enc, const float* __restrict__ cw,
    const float* __restrict__ cb, float* __restrict__ flow,
    float* __restrict__ mask)
{
    int bid = blockIdx.x;                                 // 4096 blocks
    int wb  = (bid & 7) * (CONV8_BLOCKS / 8) + (bid >> 3);
    int px0 = HALF_PIX + wb * 256;
    int n = px0 >> 18;
    int h = (px0 >> 9) & (HH - 1);

    int tid  = threadIdx.x;
    int wv   = tid >> 6;
    int lane = tid & 63;
    int pg   = lane >> 3;                                 // 0..7
    int c4   = lane & 7;

    int wbase = (px0 & (WW - 1)) + wv * 64;               // wave = 64 px
    int pxb   = wbase + pg * 8;                           // thread's 8 px

    const float4* cwB = reinterpret_cast<const float4*>(cw) + c4 * 3;
    const float* imgbase = enc + ((size_t)n * HH) * (WW * 32);

    float acc[8][3];
#pragma unroll
    for (int p = 0; p < 8; ++p)
        acc[p][0] = acc[p][1] = acc[p][2] = 0.0f;

    bool edge = (wbase == 0) || (wbase == WW - 64);       // wave-uniform

#pragma unroll
    for (int kh = 0; kh < 3; ++kh) {
        int hr = h + kh - 1;
        if ((unsigned)hr >= (unsigned)HH) continue;
        const float* rowp = imgbase + (size_t)hr * (WW * 32);

        float4 win[10];                                   // cols pxb-1..pxb+8
        if (!edge) {
            const float* pB = rowp + (pxb - 1) * 32 + c4 * 4;
#pragma unroll
            for (int j = 0; j < 10; ++j)
                win[j] = *reinterpret_cast<const float4*>(pB + j * 32);
        } else {
#pragma unroll
            for (int j = 0; j < 10; ++j) {
                int col = pxb + j - 1;
                win[j] = make_float4(0.f, 0.f, 0.f, 0.f);
                if ((unsigned)col < (unsigned)WW)
                    win[j] = *reinterpret_cast<const float4*>(
                                 rowp + (size_t)col * 32 + c4 * 4);
            }
        }

#pragma unroll
        for (int kw = 0; kw < 3; ++kw) {
            int t = kh * 3 + kw;
            float wf[12];
            *reinterpret_cast<float4*>(&wf[0]) = cwB[t * 24 + 0];
            *reinterpret_cast<float4*>(&wf[4]) = cwB[t * 24 + 1];
            *reinterpret_cast<float4*>(&wf[8]) = cwB[t * 24 + 2];
#pragma unroll
            for (int p = 0; p < 8; ++p)
                fma12(acc[p], wf, win[p + kw]);
        }
    }

    float b0 = cb[0], b1 = cb[1], b2 = cb[2];
    size_t rowidx = ((size_t)n * HH + h) * WW;

#pragma unroll
    for (int p = 0; p < 8; ++p) {
#pragma unroll
        for (int off = 1; off < 8; off <<= 1) {
            acc[p][0] += __shfl_xor(acc[p][0], off);
            acc[p][1] += __shfl_xor(acc[p][1], off);
            acc[p][2] += __shfl_xor(acc[p][2], off);
        }
    }
    if (c4 == 0) {
        float fl16[16], mk8[8];
#pragma unroll
        for (int p = 0; p < 8; ++p) {
            fl16[p * 2 + 0] = tanh_fast(acc[p][0] + b0);
            fl16[p * 2 + 1] = tanh_fast(acc[p][1] + b1);
            mk8[p]          = tanh_fast(acc[p][2] + b2);
        }
        size_t idx = rowidx + (size_t)pxb;
        float4* fp = reinterpret_cast<float4*>(flow + idx * 2);
#pragma unroll
        for (int j = 0; j < 4; ++j)
            fp[j] = *reinterpret_cast<float4*>(&fl16[j * 4]);
        float4* mp = reinterpret_cast<float4*>(mask + idx);
        mp[0] = *reinterpret_cast<float4*>(&mk8[0]);
        mp[1] = *reinterpret_cast<float4*>(&mk8[4]);
    }
}

// ================= K2: bilinear warp + blend + TV (unchanged, ~47us) ========
__device__ __forceinline__ void bilerp_h(const __half* __restrict__ img,
                                         float ch, float cwv, float out[3])
{
    float hp = (ch + 1.0f) * 255.5f;
    float wp = (cwv + 1.0f) * 255.5f;
    int h0 = (int)floorf(hp);
    int w0 = (int)floorf(wp);
    int h1  = min(max(h0 + 1, 0), HH - 1);
    int w1  = min(max(w0 + 1, 0), WW - 1);
    int h0c = min(max(h0, 0), HH - 1);
    int w0c = min(max(w0, 0), WW - 1);
    float wh = (float)h1 - hp;
    float wv = (float)w1 - wp;
    float w_ru = wh * wv;
    float w_rd = (1.0f - wh) * wv;
    float w_lu = wh * (1.0f - wv);
    float w_ld = (1.0f - wh) * (1.0f - wv);

    int q = min(w0c, WW - 2);
    bool Ahi = (w0c != q);
    bool Bhi = (w1 == q + 1);
    float4 U = *reinterpret_cast<const float4*>(img + (size_t)(((h0c << 9) + q) << 2));
    float4 D = *reinterpret_cast<const float4*>(img + (size_t)(((h1  << 9) + q) << 2));
    float ru_ab = Ahi ? U.z : U.x, ru_c = Ahi ? U.w : U.y;
    float rd_ab = Ahi ? D.z : D.x, rd_c = Ahi ? D.w : D.y;
    float lu_ab = Bhi ? U.z : U.x, lu_c = Bhi ? U.w : U.y;
    float ld_ab = Bhi ? D.z : D.x, ld_c = Bhi ? D.w : D.y;

    float2 ruA = __half22float2(*reinterpret_cast<__half2*>(&ru_ab));
    float2 rdA = __half22float2(*reinterpret_cast<__half2*>(&rd_ab));
    float2 luA = __half22float2(*reinterpret_cast<__half2*>(&lu_ab));
    float2 ldA = __half22float2(*reinterpret_cast<__half2*>(&ld_ab));
    float ruZ = __half2float(reinterpret_cast<__half2*>(&ru_c)->x);
    float rdZ = __half2float(reinterpret_cast<__half2*>(&rd_c)->x);
    float luZ = __half2float(reinterpret_cast<__half2*>(&lu_c)->x);
    float ldZ = __half2float(reinterpret_cast<__half2*>(&ld_c)->x);

    out[0] = w_ru * ruA.x + w_rd * rdA.x + w_lu * luA.x + w_ld * ldA.x;
    out[1] = w_ru * ruA.y + w_rd * rdA.y + w_lu * luA.y + w_ld * ldA.y;
    out[2] = w_ru * ruZ   + w_rd * rdZ   + w_lu * luZ   + w_ld * ldZ;
}

__global__ __launch_bounds__(256, 4) void interp_tv_kernel(
    const __half* __restrict__ f0h, const __half* __restrict__ f1h,
    const float* __restrict__ flow, const float* __restrict__ mask,
    float* __restrict__ stacked, float* __restrict__ tv_out)
{
    int bid = blockIdx.x;                                  // 1024 blocks
    int wb  = (bid & 7) * (NPIX / 2048 / 8) + (bid >> 3);  // image n -> XCD n
    int idx0 = wb * 2048 + (int)threadIdx.x * 8;           // 8 adjacent px
    int w0 = idx0 & (WW - 1);
    int h  = (idx0 >> 9) & (HH - 1);
    int n  = idx0 >> 18;

    float4 fl[4];
#pragma unroll
    for (int j = 0; j < 4; ++j)
        fl[j] = *reinterpret_cast<const float4*>(flow + (size_t)idx0 * 2 + j * 4);
    float4 mkA = *reinterpret_cast<const float4*>(mask + idx0);
    float4 mkB = *reinterpret_cast<const float4*>(mask + idx0 + 4);
    const float* flp = reinterpret_cast<const float*>(fl);
    float mkp[8] = {mkA.x, mkA.y, mkA.z, mkA.w, mkB.x, mkB.y, mkB.z, mkB.w};

    float hhv = -1.0f + (float)h * (2.0f / 511.0f);

    const __half* i0 = f0h + (size_t)n * (HH * WW * 4);
    const __half* i1 = f1h + (size_t)n * (HH * WW * 4);

    float res[24];
#pragma unroll
    for (int p = 0; p < 8; ++p) {
        float wvx = -1.0f + (float)(w0 + p) * (2.0f / 511.0f);
        float fx = flp[p * 2], fy = flp[p * 2 + 1];
        float o0[3], o1[3];
        bilerp_h(i0, hhv + fx * 0.5f, wvx + fy * 0.5f, o0);
        bilerp_h(i1, hhv - fx * 0.5f, wvx - fy * 0.5f, o1);
        float m = 0.5f * (1.0f + mkp[p]), om = 1.0f - m;
#pragma unroll
        for (int c = 0; c < 3; ++c)
            res[p * 3 + c] = m * o0[c] + om * o1[c];
    }
    float4* sp = reinterpret_cast<float4*>(stacked + (size_t)idx0 * 3);
#pragma unroll
    for (int j = 0; j < 6; ++j)
        sp[j] = make_float4(res[j * 4], res[j * 4 + 1],
                            res[j * 4 + 2], res[j * 4 + 3]);

    float tvf = 0.0f, tvm = 0.0f;
#pragma unroll
    for (int p = 0; p < 7; ++p) {
        tvf += fabsf(flp[p * 2 + 2] - flp[p * 2])
             + fabsf(flp[p * 2 + 3] - flp[p * 2 + 1]);
        tvm += fabsf(mkp[p + 1] - mkp[p]);
    }
    if (w0 < WW - 8) {
        float2 flr = *reinterpret_cast<const float2*>(flow + (size_t)(idx0 + 8) * 2);
        float  mkr = mask[idx0 + 8];
        tvf += fabsf(flr.x - flp[14]) + fabsf(flr.y - flp[15]);
        tvm += fabsf(mkr - mkp[7]);
    }
    if (h < HH - 1) {
#pragma unroll
        for (int j = 0; j < 4; ++j) {
            float4 fd = *reinterpret_cast<const float4*>(
                            flow + (size_t)(idx0 + WW) * 2 + j * 4);
            tvf += fabsf(fd.x - flp[j * 4 + 0]) + fabsf(fd.y - flp[j * 4 + 1])
                 + fabsf(fd.z - flp[j * 4 + 2]) + fabsf(fd.w - flp[j * 4 + 3]);
        }
        float4 mdA = *reinterpret_cast<const float4*>(mask + idx0 + WW);
        float4 mdB = *reinterpret_cast<const float4*>(mask + idx0 + WW + 4);
        tvm += fabsf(mdA.x - mkp[0]) + fabsf(mdA.y - mkp[1])
             + fabsf(mdA.z - mkp[2]) + fabsf(mdA.w - mkp[3])
             + fabsf(mdB.x - mkp[4]) + fabsf(mdB.y - mkp[5])
             + fabsf(mdB.z - mkp[6]) + fabsf(mdB.w - mkp[7]);
    }
    float tv = GAMMA_FLOW * tvf + GAMMA_MASK * tvm;
#pragma unroll
    for (int off = 32; off > 0; off >>= 1) tv += __shfl_xor(tv, off);
    if ((threadIdx.x & 63) == 0) atomicAdd(tv_out, tv * INV_TOTAL);
}

extern "C" void kernel_launch(void* const* d_in, const int* in_sizes, int n_in,
                              void* d_out, int out_size, void* d_ws, size_t ws_size,
                              hipStream_t stream)
{
    const float* frames  = (const float*)d_in[0];
    const float* encoded = (const float*)d_in[1];
    const float* conv_w  = (const float*)d_in[2];
    const float* conv_b  = (const float*)d_in[3];

    float* out     = (float*)d_out;
    float* stacked = out;                       // NPIX*3
    float* flow    = out + (size_t)NPIX * 3;    // NPIX*2
    float* tv      = out + (size_t)NPIX * 5;    // 1

    const size_t frame_bytes = (size_t)NPIX * 4 * sizeof(__half); // 16 MiB each
    __half* f0h = (__half*)d_ws;
    __half* f1h = (__half*)((char*)d_ws + frame_bytes);
    float*  mask = (float*)((char*)d_ws + 2 * frame_bytes);

    fat_kernel<<<FAT_BLOCKS, 256, 0, stream>>>(
        encoded, conv_w, conv_b, frames, flow, mask, f0h, f1h, tv);
    conv8_kernel<<<CONV8_BLOCKS, 256, 0, stream>>>(
        encoded, conv_w, conv_b, flow, mask);
    interp_tv_kernel<<<NPIX / 2048, 256, 0, stream>>>(
        f0h, f1h, flow, mask, stacked, tv);
}

// Round 17
// 222.797 us; speedup vs baseline: 1.2269x; 1.2269x over previous
//
#include <hip/hip_runtime.h>
#include <hip/hip_fp16.h>
#include <math.h>

#define HH 512
#define WW 512
#define NIMG 8
#define NPIX (NIMG * HH * WW)          // 2,097,152
#define GAMMA_FLOW 0.001f
#define GAMMA_MASK 0.0005f
#define INV_TOTAL (1.0f / (float)(NPIX * 3))

#define CVT_BLOCKS  (NPIX / 256)       // 8192
#define CONV_BLOCKS (NPIX / 128)       // 16384
#define FAT_BLOCKS  (CVT_BLOCKS + CONV_BLOCKS)  // 24576

__device__ __forceinline__ float tanh_fast(float x)
{
    float e = __expf(2.0f * x);
    return 1.0f - 2.0f / (e + 1.0f);
}

__device__ __forceinline__ void fma12(float acc[3], const float wf[12],
                                      float4 x)
{
    float xv[4] = {x.x, x.y, x.z, x.w};
#pragma unroll
    for (int k = 0; k < 4; ++k) {
        acc[0] = fmaf(xv[k], wf[k * 3 + 0], acc[0]);
        acc[1] = fmaf(xv[k], wf[k * 3 + 1], acc[1]);
        acc[2] = fmaf(xv[k], wf[k * 3 + 2], acc[2]);
    }
}

// ========== K1 (fat): bid%3==0 -> cvt block ; else -> conv block ============
// r15-proven config (224us total). %3 interleave is coprime to the 8-XCD
// round-robin (r16 lesson: bid&1 pinned conv to odd XCDs -> half machine).
// Conv: 4 ADJACENT px/thread, 6-wide sliding register window -> 18 enc
// loads/thread. (256,4) = the only budget (64) this kernel fits spill-free.
__global__ __launch_bounds__(256, 4) void fat_kernel(
    const float* __restrict__ enc, const float* __restrict__ cw,
    const float* __restrict__ cb, const float* __restrict__ frames,
    float* __restrict__ flow, float* __restrict__ mask,
    __half* __restrict__ f0h, __half* __restrict__ f1h,
    float* __restrict__ tv_out)
{
    int bid = blockIdx.x;

    if (bid % 3 == 0) {
        // ---------------- cvt: fp32 NHWC(6) -> two planar fp16(4) ----------
        int ci = bid / 3;                              // 0..8191
        int t  = ci * 256 + threadIdx.x;               // one pixel
        if (t == 0) tv_out[0] = 0.0f;
        const float2* fp = reinterpret_cast<const float2*>(frames + (size_t)t * 6);
        float2 v0 = fp[0], v1 = fp[1], v2 = fp[2];
        __half2 a = __floats2half2_rn(v0.x, v0.y);
        __half2 b = __floats2half2_rn(v1.x, 0.0f);
        __half2 c = __floats2half2_rn(v1.y, v2.x);
        __half2 d = __floats2half2_rn(v2.y, 0.0f);
        __half2* p0 = reinterpret_cast<__half2*>(f0h) + (size_t)t * 2;
        __half2* p1 = reinterpret_cast<__half2*>(f1h) + (size_t)t * 2;
        p0[0] = a; p0[1] = b;
        p1[0] = c; p1[1] = d;
        return;
    }

    // ---------------- conv: 3x3x32->3 + tanh, sliding window ---------------
    int ci  = bid - (bid + 2) / 3;                        // 0..16383
    int wb  = (ci & 7) * (CONV_BLOCKS / 8) + (ci >> 3);   // image n -> XCD n
    int px0 = wb * 128;
    int n = px0 >> 18;
    int h = (px0 >> 9) & (HH - 1);

    int tid  = threadIdx.x;
    int wv   = tid >> 6;
    int lane = tid & 63;
    int pg   = lane >> 3;                                 // pixel group (0..7)
    int c4   = lane & 7;                                  // channel chunk

    int wbase = (px0 & (WW - 1)) + wv * 32;               // wave's 32-px seg
    int pxb   = wbase + pg * 4;                           // thread's 4 px base

    const float4* cwB = reinterpret_cast<const float4*>(cw) + c4 * 3;
    const float* imgbase = enc + ((size_t)n * HH) * (WW * 32);

    float acc[4][3];
#pragma unroll
    for (int p = 0; p < 4; ++p)
        acc[p][0] = acc[p][1] = acc[p][2] = 0.0f;

    bool edge = (wbase == 0) || (wbase == WW - 32);       // wave-uniform

#pragma unroll
    for (int kh = 0; kh < 3; ++kh) {
        int hr = h + kh - 1;
        if ((unsigned)hr >= (unsigned)HH) continue;       // block-uniform
        const float* rowp = imgbase + (size_t)hr * (WW * 32);

        float4 win[6];                                    // cols pxb-1..pxb+4
        if (!edge) {
            const float* pB = rowp + (pxb - 1) * 32 + c4 * 4;
#pragma unroll
            for (int j = 0; j < 6; ++j)
                win[j] = *reinterpret_cast<const float4*>(pB + j * 32);
        } else {
#pragma unroll
            for (int j = 0; j < 6; ++j) {
                int col = pxb + j - 1;
                win[j] = make_float4(0.f, 0.f, 0.f, 0.f);
                if ((unsigned)col < (unsigned)WW)
                    win[j] = *reinterpret_cast<const float4*>(
                                 rowp + (size_t)col * 32 + c4 * 4);
            }
        }

#pragma unroll
        for (int kw = 0; kw < 3; ++kw) {
            int t = kh * 3 + kw;
            float wf[12];
            *reinterpret_cast<float4*>(&wf[0]) = cwB[t * 24 + 0];
            *reinterpret_cast<float4*>(&wf[4]) = cwB[t * 24 + 1];
            *reinterpret_cast<float4*>(&wf[8]) = cwB[t * 24 + 2];
#pragma unroll
            for (int p = 0; p < 4; ++p)
                fma12(acc[p], wf, win[p + kw]);
        }
    }

    float b0 = cb[0], b1 = cb[1], b2 = cb[2];
    size_t rowidx = ((size_t)n * HH + h) * WW;

#pragma unroll
    for (int p = 0; p < 4; ++p) {
#pragma unroll
        for (int off = 1; off < 8; off <<= 1) {           // reduce over c4
            acc[p][0] += __shfl_xor(acc[p][0], off);
            acc[p][1] += __shfl_xor(acc[p][1], off);
            acc[p][2] += __shfl_xor(acc[p][2], off);
        }
    }
    if (c4 == 0) {
#pragma unroll
        for (int p = 0; p < 4; ++p) {
            size_t idx = rowidx + (size_t)(pxb + p);
            *reinterpret_cast<float2*>(flow + idx * 2) =
                make_float2(tanh_fast(acc[p][0] + b0),
                            tanh_fast(acc[p][1] + b1));
            mask[idx] = tanh_fast(acc[p][2] + b2);
        }
    }
}

// ================= K2: bilinear warp + blend + TV (unchanged, ~47us) ========
__device__ __forceinline__ void bilerp_h(const __half* __restrict__ img,
                                         float ch, float cwv, float out[3])
{
    float hp = (ch + 1.0f) * 255.5f;
    float wp = (cwv + 1.0f) * 255.5f;
    int h0 = (int)floorf(hp);
    int w0 = (int)floorf(wp);
    int h1  = min(max(h0 + 1, 0), HH - 1);
    int w1  = min(max(w0 + 1, 0), WW - 1);
    int h0c = min(max(h0, 0), HH - 1);
    int w0c = min(max(w0, 0), WW - 1);
    float wh = (float)h1 - hp;
    float wv = (float)w1 - wp;
    float w_ru = wh * wv;
    float w_rd = (1.0f - wh) * wv;
    float w_lu = wh * (1.0f - wv);
    float w_ld = (1.0f - wh) * (1.0f - wv);

    int q = min(w0c, WW - 2);
    bool Ahi = (w0c != q);
    bool Bhi = (w1 == q + 1);
    float4 U = *reinterpret_cast<const float4*>(img + (size_t)(((h0c << 9) + q) << 2));
    float4 D = *reinterpret_cast<const float4*>(img + (size_t)(((h1  << 9) + q) << 2));
    float ru_ab = Ahi ? U.z : U.x, ru_c = Ahi ? U.w : U.y;
    float rd_ab = Ahi ? D.z : D.x, rd_c = Ahi ? D.w : D.y;
    float lu_ab = Bhi ? U.z : U.x, lu_c = Bhi ? U.w : U.y;
    float ld_ab = Bhi ? D.z : D.x, ld_c = Bhi ? D.w : D.y;

    float2 ruA = __half22float2(*reinterpret_cast<__half2*>(&ru_ab));
    float2 rdA = __half22float2(*reinterpret_cast<__half2*>(&rd_ab));
    float2 luA = __half22float2(*reinterpret_cast<__half2*>(&lu_ab));
    float2 ldA = __half22float2(*reinterpret_cast<__half2*>(&ld_ab));
    float ruZ = __half2float(reinterpret_cast<__half2*>(&ru_c)->x);
    float rdZ = __half2float(reinterpret_cast<__half2*>(&rd_c)->x);
    float luZ = __half2float(reinterpret_cast<__half2*>(&lu_c)->x);
    float ldZ = __half2float(reinterpret_cast<__half2*>(&ld_c)->x);

    out[0] = w_ru * ruA.x + w_rd * rdA.x + w_lu * luA.x + w_ld * ldA.x;
    out[1] = w_ru * ruA.y + w_rd * rdA.y + w_lu * luA.y + w_ld * ldA.y;
    out[2] = w_ru * ruZ   + w_rd * rdZ   + w_lu * luZ   + w_ld * ldZ;
}

__global__ __launch_bounds__(256, 4) void interp_tv_kernel(
    const __half* __restrict__ f0h, const __half* __restrict__ f1h,
    const float* __restrict__ flow, const float* __restrict__ mask,
    float* __restrict__ stacked, float* __restrict__ tv_out)
{
    int bid = blockIdx.x;                                  // 1024 blocks
    int wb  = (bid & 7) * (NPIX / 2048 / 8) + (bid >> 3);  // image n -> XCD n
    int idx0 = wb * 2048 + (int)threadIdx.x * 8;           // 8 adjacent px
    int w0 = idx0 & (WW - 1);
    int h  = (idx0 >> 9) & (HH - 1);
    int n  = idx0 >> 18;

    float4 fl[4];
#pragma unroll
    for (int j = 0; j < 4; ++j)
        fl[j] = *reinterpret_cast<const float4*>(flow + (size_t)idx0 * 2 + j * 4);
    float4 mkA = *reinterpret_cast<const float4*>(mask + idx0);
    float4 mkB = *reinterpret_cast<const float4*>(mask + idx0 + 4);
    const float* flp = reinterpret_cast<const float*>(fl);
    float mkp[8] = {mkA.x, mkA.y, mkA.z, mkA.w, mkB.x, mkB.y, mkB.z, mkB.w};

    float hhv = -1.0f + (float)h * (2.0f / 511.0f);

    const __half* i0 = f0h + (size_t)n * (HH * WW * 4);
    const __half* i1 = f1h + (size_t)n * (HH * WW * 4);

    float res[24];
#pragma unroll
    for (int p = 0; p < 8; ++p) {
        float wvx = -1.0f + (float)(w0 + p) * (2.0f / 511.0f);
        float fx = flp[p * 2], fy = flp[p * 2 + 1];
        float o0[3], o1[3];
        bilerp_h(i0, hhv + fx * 0.5f, wvx + fy * 0.5f, o0);
        bilerp_h(i1, hhv - fx * 0.5f, wvx - fy * 0.5f, o1);
        float m = 0.5f * (1.0f + mkp[p]), om = 1.0f - m;
#pragma unroll
        for (int c = 0; c < 3; ++c)
            res[p * 3 + c] = m * o0[c] + om * o1[c];
    }
    float4* sp = reinterpret_cast<float4*>(stacked + (size_t)idx0 * 3);
#pragma unroll
    for (int j = 0; j < 6; ++j)
        sp[j] = make_float4(res[j * 4], res[j * 4 + 1],
                            res[j * 4 + 2], res[j * 4 + 3]);

    float tvf = 0.0f, tvm = 0.0f;
#pragma unroll
    for (int p = 0; p < 7; ++p) {
        tvf += fabsf(flp[p * 2 + 2] - flp[p * 2])
             + fabsf(flp[p * 2 + 3] - flp[p * 2 + 1]);
        tvm += fabsf(mkp[p + 1] - mkp[p]);
    }
    if (w0 < WW - 8) {
        float2 flr = *reinterpret_cast<const float2*>(flow + (size_t)(idx0 + 8) * 2);
        float  mkr = mask[idx0 + 8];
        tvf += fabsf(flr.x - flp[14]) + fabsf(flr.y - flp[15]);
        tvm += fabsf(mkr - mkp[7]);
    }
    if (h < HH - 1) {
#pragma unroll
        for (int j = 0; j < 4; ++j) {
            float4 fd = *reinterpret_cast<const float4*>(
                            flow + (size_t)(idx0 + WW) * 2 + j * 4);
            tvf += fabsf(fd.x - flp[j * 4 + 0]) + fabsf(fd.y - flp[j * 4 + 1])
                 + fabsf(fd.z - flp[j * 4 + 2]) + fabsf(fd.w - flp[j * 4 + 3]);
        }
        float4 mdA = *reinterpret_cast<const float4*>(mask + idx0 + WW);
        float4 mdB = *reinterpret_cast<const float4*>(mask + idx0 + WW + 4);
        tvm += fabsf(mdA.x - mkp[0]) + fabsf(mdA.y - mkp[1])
             + fabsf(mdA.z - mkp[2]) + fabsf(mdA.w - mkp[3])
             + fabsf(mdB.x - mkp[4]) + fabsf(mdB.y - mkp[5])
             + fabsf(mdB.z - mkp[6]) + fabsf(mdB.w - mkp[7]);
    }
    float tv = GAMMA_FLOW * tvf + GAMMA_MASK * tvm;
#pragma unroll
    for (int off = 32; off > 0; off >>= 1) tv += __shfl_xor(tv, off);
    if ((threadIdx.x & 63) == 0) atomicAdd(tv_out, tv * INV_TOTAL);
}

extern "C" void kernel_launch(void* const* d_in, const int* in_sizes, int n_in,
                              void* d_out, int out_size, void* d_ws, size_t ws_size,
                              hipStream_t stream)
{
    const float* frames  = (const float*)d_in[0];
    const float* encoded = (const float*)d_in[1];
    const float* conv_w  = (const float*)d_in[2];
    const float* conv_b  = (const float*)d_in[3];

    float* out     = (float*)d_out;
    float* stacked = out;                       // NPIX*3
    float* flow    = out + (size_t)NPIX * 3;    // NPIX*2
    float* tv      = out + (size_t)NPIX * 5;    // 1

    const size_t frame_bytes = (size_t)NPIX * 4 * sizeof(__half); // 16 MiB each
    __half* f0h = (__half*)d_ws;
    __half* f1h = (__half*)((char*)d_ws + frame_bytes);
    float*  mask = (float*)((char*)d_ws + 2 * frame_bytes);

    fat_kernel<<<FAT_BLOCKS, 256, 0, stream>>>(
        encoded, conv_w, conv_b, frames, flow, mask, f0h, f1h, tv);
    interp_tv_kernel<<<NPIX / 2048, 256, 0, stream>>>(
        f0h, f1h, flow, mask, stacked, tv);
}

// Round 18
// 198.289 us; speedup vs baseline: 1.3785x; 1.1236x over previous
//
#include <hip/hip_runtime.h>
#include <hip/hip_fp16.h>
#include <math.h>

#define HH 512
#define WW 512
#define NIMG 8
#define NPIX (NIMG * HH * WW)          // 2,097,152
#define GAMMA_FLOW 0.001f
#define GAMMA_MASK 0.0005f
#define INV_TOTAL (1.0f / (float)(NPIX * 3))

#define CVT_BLOCKS  (NPIX / 256)       // 8192
#define CONV_BLOCKS (NPIX / 128)       // 16384
#define FAT_BLOCKS  (CVT_BLOCKS + CONV_BLOCKS)  // 24576

__device__ __forceinline__ float tanh_fast(float x)
{
    float e = __expf(2.0f * x);
    return 1.0f - 2.0f / (e + 1.0f);
}

// v_pk_fma_f32: d.lo = a.lo*b.lo + c.lo ; d.hi = a.hi*b.hi + c.hi
__device__ __forceinline__ float2 pk_fma(float2 a, float2 b, float2 c)
{
    float2 d;
    asm("v_pk_fma_f32 %0, %1, %2, %3" : "=v"(d) : "v"(a), "v"(b), "v"(c));
    return d;
}

// ========== K1 (fat): bid%3==0 -> cvt block ; else -> conv block ============
// r17 structure; conv FMA path switched to packed fp32:
//   weights transposed to LDS [tap][out][ch] (3.4KB, once/block) so channel
//   pairs are contiguous -> per (tap,out,px): 2 pk_fma on (win.xy,w4.xy) /
//   (win.zw,w4.zw) aligned reg-pairs. 432 fma -> 216 pk_fma per thread.
//   Weight fetch: 27 imm-offset ds_read_b128 (vs 27 global float4).
__global__ __launch_bounds__(256, 4) void fat_kernel(
    const float* __restrict__ enc, const float* __restrict__ cw,
    const float* __restrict__ cb, const float* __restrict__ frames,
    float* __restrict__ flow, float* __restrict__ mask,
    __half* __restrict__ f0h, __half* __restrict__ f1h,
    float* __restrict__ tv_out)
{
    __shared__ float wlds[864];                           // [9][3][32]

    int bid = blockIdx.x;

    if (bid % 3 == 0) {
        // ---------------- cvt: fp32 NHWC(6) -> two planar fp16(4) ----------
        int ci = bid / 3;                              // 0..8191
        int t  = ci * 256 + threadIdx.x;               // one pixel
        if (t == 0) tv_out[0] = 0.0f;
        const float2* fp = reinterpret_cast<const float2*>(frames + (size_t)t * 6);
        float2 v0 = fp[0], v1 = fp[1], v2 = fp[2];
        __half2 a = __floats2half2_rn(v0.x, v0.y);
        __half2 b = __floats2half2_rn(v1.x, 0.0f);
        __half2 c = __floats2half2_rn(v1.y, v2.x);
        __half2 d = __floats2half2_rn(v2.y, 0.0f);
        __half2* p0 = reinterpret_cast<__half2*>(f0h) + (size_t)t * 2;
        __half2* p1 = reinterpret_cast<__half2*>(f1h) + (size_t)t * 2;
        p0[0] = a; p0[1] = b;
        p1[0] = c; p1[1] = d;
        return;
    }

    // ---------------- conv: 3x3x32->3 + tanh, sliding window + pk_fma ------
    int ci  = bid - (bid + 2) / 3;                        // 0..16383
    int wb  = (ci & 7) * (CONV_BLOCKS / 8) + (ci >> 3);   // image n -> XCD n
    int px0 = wb * 128;
    int n = px0 >> 18;
    int h = (px0 >> 9) & (HH - 1);

    int tid  = threadIdx.x;

    // stage transposed weights: wlds[t*96 + o*32 + c] = cw[(t*32+c)*3 + o]
    for (int e = tid; e < 864; e += 256) {
        int t = e / 96;
        int r = e - t * 96;
        int o = r >> 5;
        int c = r & 31;
        wlds[e] = cw[(t * 32 + c) * 3 + o];
    }
    __syncthreads();

    int wv   = tid >> 6;
    int lane = tid & 63;
    int pg   = lane >> 3;                                 // pixel group (0..7)
    int c4   = lane & 7;                                  // channel chunk

    int wbase = (px0 & (WW - 1)) + wv * 32;               // wave's 32-px seg
    int pxb   = wbase + pg * 4;                           // thread's 4 px base

    const float* imgbase = enc + ((size_t)n * HH) * (WW * 32);
    const float* wbase_lds = &wlds[c4 * 4];

    float2 pacc[4][3];
#pragma unroll
    for (int p = 0; p < 4; ++p)
#pragma unroll
        for (int o = 0; o < 3; ++o)
            pacc[p][o] = make_float2(0.f, 0.f);

    bool edge = (wbase == 0) || (wbase == WW - 32);       // wave-uniform

#pragma unroll
    for (int kh = 0; kh < 3; ++kh) {
        int hr = h + kh - 1;
        if ((unsigned)hr >= (unsigned)HH) continue;       // block-uniform
        const float* rowp = imgbase + (size_t)hr * (WW * 32);

        float4 win[6];                                    // cols pxb-1..pxb+4
        if (!edge) {
            const float* pB = rowp + (pxb - 1) * 32 + c4 * 4;
#pragma unroll
            for (int j = 0; j < 6; ++j)
                win[j] = *reinterpret_cast<const float4*>(pB + j * 32);
        } else {
#pragma unroll
            for (int j = 0; j < 6; ++j) {
                int col = pxb + j - 1;
                win[j] = make_float4(0.f, 0.f, 0.f, 0.f);
                if ((unsigned)col < (unsigned)WW)
                    win[j] = *reinterpret_cast<const float4*>(
                                 rowp + (size_t)col * 32 + c4 * 4);
            }
        }

#pragma unroll
        for (int kw = 0; kw < 3; ++kw) {
            int t = kh * 3 + kw;
#pragma unroll
            for (int o = 0; o < 3; ++o) {
                float4 w4 = *reinterpret_cast<const float4*>(
                                wbase_lds + t * 96 + o * 32);
                float2 wlo = make_float2(w4.x, w4.y);
                float2 whi = make_float2(w4.z, w4.w);
#pragma unroll
                for (int p = 0; p < 4; ++p) {
                    float2 xlo = make_float2(win[p + kw].x, win[p + kw].y);
                    float2 xhi = make_float2(win[p + kw].z, win[p + kw].w);
                    pacc[p][o] = pk_fma(xlo, wlo, pacc[p][o]);
                    pacc[p][o] = pk_fma(xhi, whi, pacc[p][o]);
                }
            }
        }
    }

    float b0 = cb[0], b1 = cb[1], b2 = cb[2];
    size_t rowidx = ((size_t)n * HH + h) * WW;

    float acc[4][3];
#pragma unroll
    for (int p = 0; p < 4; ++p) {
#pragma unroll
        for (int o = 0; o < 3; ++o)
            acc[p][o] = pacc[p][o].x + pacc[p][o].y;
#pragma unroll
        for (int off = 1; off < 8; off <<= 1) {           // reduce over c4
            acc[p][0] += __shfl_xor(acc[p][0], off);
            acc[p][1] += __shfl_xor(acc[p][1], off);
            acc[p][2] += __shfl_xor(acc[p][2], off);
        }
    }
    if (c4 == 0) {
#pragma unroll
        for (int p = 0; p < 4; ++p) {
            size_t idx = rowidx + (size_t)(pxb + p);
            *reinterpret_cast<float2*>(flow + idx * 2) =
                make_float2(tanh_fast(acc[p][0] + b0),
                            tanh_fast(acc[p][1] + b1));
            mask[idx] = tanh_fast(acc[p][2] + b2);
        }
    }
}

// ================= K2: bilinear warp + blend + TV (unchanged, ~47us) ========
__device__ __forceinline__ void bilerp_h(const __half* __restrict__ img,
                                         float ch, float cwv, float out[3])
{
    float hp = (ch + 1.0f) * 255.5f;
    float wp = (cwv + 1.0f) * 255.5f;
    int h0 = (int)floorf(hp);
    int w0 = (int)floorf(wp);
    int h1  = min(max(h0 + 1, 0), HH - 1);
    int w1  = min(max(w0 + 1, 0), WW - 1);
    int h0c = min(max(h0, 0), HH - 1);
    int w0c = min(max(w0, 0), WW - 1);
    float wh = (float)h1 - hp;
    float wv = (float)w1 - wp;
    float w_ru = wh * wv;
    float w_rd = (1.0f - wh) * wv;
    float w_lu = wh * (1.0f - wv);
    float w_ld = (1.0f - wh) * (1.0f - wv);

    int q = min(w0c, WW - 2);
    bool Ahi = (w0c != q);
    bool Bhi = (w1 == q + 1);
    float4 U = *reinterpret_cast<const float4*>(img + (size_t)(((h0c << 9) + q) << 2));
    float4 D = *reinterpret_cast<const float4*>(img + (size_t)(((h1  << 9) + q) << 2));
    float ru_ab = Ahi ? U.z : U.x, ru_c = Ahi ? U.w : U.y;
    float rd_ab = Ahi ? D.z : D.x, rd_c = Ahi ? D.w : D.y;
    float lu_ab = Bhi ? U.z : U.x, lu_c = Bhi ? U.w : U.y;
    float ld_ab = Bhi ? D.z : D.x, ld_c = Bhi ? D.w : D.y;

    float2 ruA = __half22float2(*reinterpret_cast<__half2*>(&ru_ab));
    float2 rdA = __half22float2(*reinterpret_cast<__half2*>(&rd_ab));
    float2 luA = __half22float2(*reinterpret_cast<__half2*>(&lu_ab));
    float2 ldA = __half22float2(*reinterpret_cast<__half2*>(&ld_ab));
    float ruZ = __half2float(reinterpret_cast<__half2*>(&ru_c)->x);
    float rdZ = __half2float(reinterpret_cast<__half2*>(&rd_c)->x);
    float luZ = __half2float(reinterpret_cast<__half2*>(&lu_c)->x);
    float ldZ = __half2float(reinterpret_cast<__half2*>(&ld_c)->x);

    out[0] = w_ru * ruA.x + w_rd * rdA.x + w_lu * luA.x + w_ld * ldA.x;
    out[1] = w_ru * ruA.y + w_rd * rdA.y + w_lu * luA.y + w_ld * ldA.y;
    out[2] = w_ru * ruZ   + w_rd * rdZ   + w_lu * luZ   + w_ld * ldZ;
}

__global__ __launch_bounds__(256, 4) void interp_tv_kernel(
    const __half* __restrict__ f0h, const __half* __restrict__ f1h,
    const float* __restrict__ flow, const float* __restrict__ mask,
    float* __restrict__ stacked, float* __restrict__ tv_out)
{
    int bid = blockIdx.x;                                  // 1024 blocks
    int wb  = (bid & 7) * (NPIX / 2048 / 8) + (bid >> 3);  // image n -> XCD n
    int idx0 = wb * 2048 + (int)threadIdx.x * 8;           // 8 adjacent px
    int w0 = idx0 & (WW - 1);
    int h  = (idx0 >> 9) & (HH - 1);
    int n  = idx0 >> 18;

    float4 fl[4];
#pragma unroll
    for (int j = 0; j < 4; ++j)
        fl[j] = *reinterpret_cast<const float4*>(flow + (size_t)idx0 * 2 + j * 4);
    float4 mkA = *reinterpret_cast<const float4*>(mask + idx0);
    float4 mkB = *reinterpret_cast<const float4*>(mask + idx0 + 4);
    const float* flp = reinterpret_cast<const float*>(fl);
    float mkp[8] = {mkA.x, mkA.y, mkA.z, mkA.w, mkB.x, mkB.y, mkB.z, mkB.w};

    float hhv = -1.0f + (float)h * (2.0f / 511.0f);

    const __half* i0 = f0h + (size_t)n * (HH * WW * 4);
    const __half* i1 = f1h + (size_t)n * (HH * WW * 4);

    float res[24];
#pragma unroll
    for (int p = 0; p < 8; ++p) {
        float wvx = -1.0f + (float)(w0 + p) * (2.0f / 511.0f);
        float fx = flp[p * 2], fy = flp[p * 2 + 1];
        float o0[3], o1[3];
        bilerp_h(i0, hhv + fx * 0.5f, wvx + fy * 0.5f, o0);
        bilerp_h(i1, hhv - fx * 0.5f, wvx - fy * 0.5f, o1);
        float m = 0.5f * (1.0f + mkp[p]), om = 1.0f - m;
#pragma unroll
        for (int c = 0; c < 3; ++c)
            res[p * 3 + c] = m * o0[c] + om * o1[c];
    }
    float4* sp = reinterpret_cast<float4*>(stacked + (size_t)idx0 * 3);
#pragma unroll
    for (int j = 0; j < 6; ++j)
        sp[j] = make_float4(res[j * 4], res[j * 4 + 1],
                            res[j * 4 + 2], res[j * 4 + 3]);

    float tvf = 0.0f, tvm = 0.0f;
#pragma unroll
    for (int p = 0; p < 7; ++p) {
        tvf += fabsf(flp[p * 2 + 2] - flp[p * 2])
             + fabsf(flp[p * 2 + 3] - flp[p * 2 + 1]);
        tvm += fabsf(mkp[p + 1] - mkp[p]);
    }
    if (w0 < WW - 8) {
        float2 flr = *reinterpret_cast<const float2*>(flow + (size_t)(idx0 + 8) * 2);
        float  mkr = mask[idx0 + 8];
        tvf += fabsf(flr.x - flp[14]) + fabsf(flr.y - flp[15]);
        tvm += fabsf(mkr - mkp[7]);
    }
    if (h < HH - 1) {
#pragma unroll
        for (int j = 0; j < 4; ++j) {
            float4 fd = *reinterpret_cast<const float4*>(
                            flow + (size_t)(idx0 + WW) * 2 + j * 4);
            tvf += fabsf(fd.x - flp[j * 4 + 0]) + fabsf(fd.y - flp[j * 4 + 1])
                 + fabsf(fd.z - flp[j * 4 + 2]) + fabsf(fd.w - flp[j * 4 + 3]);
        }
        float4 mdA = *reinterpret_cast<const float4*>(mask + idx0 + WW);
        float4 mdB = *reinterpret_cast<const float4*>(mask + idx0 + WW + 4);
        tvm += fabsf(mdA.x - mkp[0]) + fabsf(mdA.y - mkp[1])
             + fabsf(mdA.z - mkp[2]) + fabsf(mdA.w - mkp[3])
             + fabsf(mdB.x - mkp[4]) + fabsf(mdB.y - mkp[5])
             + fabsf(mdB.z - mkp[6]) + fabsf(mdB.w - mkp[7]);
    }
    float tv = GAMMA_FLOW * tvf + GAMMA_MASK * tvm;
#pragma unroll
    for (int off = 32; off > 0; off >>= 1) tv += __shfl_xor(tv, off);
    if ((threadIdx.x & 63) == 0) atomicAdd(tv_out, tv * INV_TOTAL);
}

extern "C" void kernel_launch(void* const* d_in, const int* in_sizes, int n_in,
                              void* d_out, int out_size, void* d_ws, size_t ws_size,
                              hipStream_t stream)
{
    const float* frames  = (const float*)d_in[0];
    const float* encoded = (const float*)d_in[1];
    const float* conv_w  = (const float*)d_in[2];
    const float* conv_b  = (const float*)d_in[3];

    float* out     = (float*)d_out;
    float* stacked = out;                       // NPIX*3
    float* flow    = out + (size_t)NPIX * 3;    // NPIX*2
    float* tv      = out + (size_t)NPIX * 5;    // 1

    const size_t frame_bytes = (size_t)NPIX * 4 * sizeof(__half); // 16 MiB each
    __half* f0h = (__half*)d_ws;
    __half* f1h = (__half*)((char*)d_ws + frame_bytes);
    float*  mask = (float*)((char*)d_ws + 2 * frame_bytes);

    fat_kernel<<<FAT_BLOCKS, 256, 0, stream>>>(
        encoded, conv_w, conv_b, frames, flow, mask, f0h, f1h, tv);
    interp_tv_kernel<<<NPIX / 2048, 256, 0, stream>>>(
        f0h, f1h, flow, mask, stacked, tv);
}